// Round 3
// baseline (6785.022 us; speedup 1.0000x reference)
//
#include <hip/hip_runtime.h>
#include <math.h>

#define TOKENS 16384
#define HIDDEN 4096
#define NE 64
#define TB 16                    // tokens per block
#define SK 64                    // k-elements per LDS stage
#define NSTAGE (HIDDEN / SK)     // 64
#define KW (SK / 4)              // 16 k's per wave per stage (split-K x4)

#define IDX_OFF 0
#define SC_OFF   (TOKENS * 2)
#define MASK_OFF (TOKENS * 4)
#define AUX_OFF  (MASK_OFF + TOKENS * 2 * NE)

// smem layout (floats):
//   [0 .. 2047]      x stage double buffer: xs(buf,t,c) = buf*1024 + t*64 + c
//   [0 .. 4095]      psum(w,t,e) = w*1024 + t*64 + e   (reuses xs after K-loop)
//   [4096 .. 4159]   fsh, [4160 .. 4223] msh
#define SMEM_FLOATS (4 * TB * NE + 2 * NE)

__global__ __launch_bounds__(256, 4)
void router_kernel(const float* __restrict__ x, const float* __restrict__ Wg,
                   const float* __restrict__ bg, float* __restrict__ out,
                   float* __restrict__ gf, float* __restrict__ gm)
{
    const int lane = threadIdx.x & 63;
    const int wv   = threadIdx.x >> 6;
    const int t0   = blockIdx.x * TB;

    __shared__ float smem[SMEM_FLOATS];
    float* fsh = smem + 4096;
    float* msh = smem + 4160;

    // staging map: thread i loads token row i/16, float4-column i%16
    const int tr  = threadIdx.x >> 4;
    const int tc4 = threadIdx.x & 15;
    const float* xrow = x + (size_t)(t0 + tr) * HIDDEN + tc4 * 4;

    const int kw = wv * KW;                       // wave's k-offset in stage
    const float* wbase = Wg + (size_t)kw * NE + lane;

    float acc[TB];
    #pragma unroll
    for (int t = 0; t < TB; ++t) acc[t] = 0.f;

    float4 xv;
    float  wa[KW], wb[KW];

    // ---- prologue: stage 0 into buf0 + wa ----
    xv = *reinterpret_cast<const float4*>(xrow);
    #pragma unroll
    for (int j = 0; j < KW; ++j) wa[j] = wbase[(size_t)j * NE];
    *reinterpret_cast<float4*>(&smem[tr * 64 + tc4 * 4]) = xv;
    __syncthreads();

    #define COMPUTE(BUF, W)                                                    \
        _Pragma("unroll")                                                      \
        for (int t = 0; t < TB; ++t) {                                         \
            const float* xr = &smem[(BUF) * 1024 + t * 64 + kw];               \
            const float4 a = *reinterpret_cast<const float4*>(xr + 0);         \
            const float4 b = *reinterpret_cast<const float4*>(xr + 4);         \
            const float4 c = *reinterpret_cast<const float4*>(xr + 8);         \
            const float4 d = *reinterpret_cast<const float4*>(xr + 12);        \
            acc[t] = fmaf(a.x, W[0],  acc[t]);                                 \
            acc[t] = fmaf(a.y, W[1],  acc[t]);                                 \
            acc[t] = fmaf(a.z, W[2],  acc[t]);                                 \
            acc[t] = fmaf(a.w, W[3],  acc[t]);                                 \
            acc[t] = fmaf(b.x, W[4],  acc[t]);                                 \
            acc[t] = fmaf(b.y, W[5],  acc[t]);                                 \
            acc[t] = fmaf(b.z, W[6],  acc[t]);                                 \
            acc[t] = fmaf(b.w, W[7],  acc[t]);                                 \
            acc[t] = fmaf(c.x, W[8],  acc[t]);                                 \
            acc[t] = fmaf(c.y, W[9],  acc[t]);                                 \
            acc[t] = fmaf(c.z, W[10], acc[t]);                                 \
            acc[t] = fmaf(c.w, W[11], acc[t]);                                 \
            acc[t] = fmaf(d.x, W[12], acc[t]);                                 \
            acc[t] = fmaf(d.y, W[13], acc[t]);                                 \
            acc[t] = fmaf(d.z, W[14], acc[t]);                                 \
            acc[t] = fmaf(d.w, W[15], acc[t]);                                 \
        }

    // ---- main loop, 2x-unrolled so wa/wb alternate without copies ----
    for (int s = 0; s < NSTAGE; s += 2) {
        // even stage s (buf0, wa); prefetch s+1
        xv = *reinterpret_cast<const float4*>(xrow + (size_t)(s + 1) * SK);
        {
            const float* wp = wbase + (size_t)(s + 1) * SK * NE;
            #pragma unroll
            for (int j = 0; j < KW; ++j) wb[j] = wp[(size_t)j * NE];
        }
        COMPUTE(0, wa)
        *reinterpret_cast<float4*>(&smem[1024 + tr * 64 + tc4 * 4]) = xv;
        __syncthreads();

        // odd stage s+1 (buf1, wb); prefetch s+2
        if (s + 2 < NSTAGE) {
            xv = *reinterpret_cast<const float4*>(xrow + (size_t)(s + 2) * SK);
            const float* wp = wbase + (size_t)(s + 2) * SK * NE;
            #pragma unroll
            for (int j = 0; j < KW; ++j) wa[j] = wp[(size_t)j * NE];
        }
        COMPUTE(1, wb)
        if (s + 2 < NSTAGE) {
            *reinterpret_cast<float4*>(&smem[tr * 64 + tc4 * 4]) = xv;
        }
        __syncthreads();
    }

    // ---- cross-wave K-reduction via LDS (psum reuses xs region) ----
    #pragma unroll
    for (int t = 0; t < TB; ++t) smem[wv * 1024 + t * 64 + lane] = acc[t];
    if (threadIdx.x < NE) { fsh[threadIdx.x] = 0.f; msh[threadIdx.x] = 0.f; }
    __syncthreads();

    // ---- epilogue: wave wv handles tokens 4*wv .. 4*wv+3 ----
    const float bias = bg[lane];
    float f_acc = 0.f, m_acc = 0.f;

    #pragma unroll
    for (int tt = 0; tt < 4; ++tt) {
        const int t = wv * 4 + tt;
        const float v = (smem[0 * 1024 + t * 64 + lane] + smem[1 * 1024 + t * 64 + lane])
                      + (smem[2 * 1024 + t * 64 + lane] + smem[3 * 1024 + t * 64 + lane])
                      + bias;

        // top-1 (value desc, index asc — matches lax.top_k tie-break)
        float v1 = v; int i1 = lane;
        #pragma unroll
        for (int off = 32; off > 0; off >>= 1) {
            const float ov = __shfl_xor(v1, off, 64);
            const int   oi = __shfl_xor(i1, off, 64);
            if (ov > v1 || (ov == v1 && oi < i1)) { v1 = ov; i1 = oi; }
        }
        // top-2
        float v2 = (lane == i1) ? -INFINITY : v; int i2 = lane;
        #pragma unroll
        for (int off = 32; off > 0; off >>= 1) {
            const float ov = __shfl_xor(v2, off, 64);
            const int   oi = __shfl_xor(i2, off, 64);
            if (ov > v2 || (ov == v2 && oi < i2)) { v2 = ov; i2 = oi; }
        }

        // full 64-way softmax (for m_i)
        const float e = expf(v - v1);
        float s = e;
        #pragma unroll
        for (int off = 32; off > 0; off >>= 1) s += __shfl_xor(s, off, 64);
        m_acc += e / s;
        f_acc += ((lane == i1) ? 1.f : 0.f) + ((lane == i2) ? 1.f : 0.f);

        // softmax over top-2 (max v1 already subtracted)
        const float p  = expf(v2 - v1);
        const float s0 = 1.f / (1.f + p);
        const float s1 = p / (1.f + p);

        const int tok = t0 + t;
        if (lane == 0) {
            out[IDX_OFF + tok * 2 + 0] = (float)i1;
            out[IDX_OFF + tok * 2 + 1] = (float)i2;
        } else if (lane == 1) {
            out[SC_OFF + tok * 2 + 0] = s0;
            out[SC_OFF + tok * 2 + 1] = s1;
        }
        out[MASK_OFF + (size_t)tok * 2 * NE + lane]      = (lane == i1) ? 1.f : 0.f;
        out[MASK_OFF + (size_t)tok * 2 * NE + NE + lane] = (lane == i2) ? 1.f : 0.f;
    }

    atomicAdd(&fsh[lane], f_acc);
    atomicAdd(&msh[lane], m_acc);
    __syncthreads();
    if (threadIdx.x < NE) {
        atomicAdd(&gf[threadIdx.x], fsh[threadIdx.x]);
        atomicAdd(&gm[threadIdx.x], msh[threadIdx.x]);
    }
}

// aux_loss = 0.01 * sum(f_i * m_i) / 64
__global__ void aux_kernel(const float* __restrict__ gf,
                           const float* __restrict__ gm,
                           float* __restrict__ out)
{
    const int lane = threadIdx.x;
    const float f = gf[lane] / (float)(TOKENS * 2);
    const float m = gm[lane] / (float)TOKENS;
    float p = f * m;
    #pragma unroll
    for (int off = 32; off > 0; off >>= 1) p += __shfl_xor(p, off, 64);
    if (lane == 0) out[AUX_OFF] = 0.01f * p / (float)NE;
}

extern "C" void kernel_launch(void* const* d_in, const int* in_sizes, int n_in,
                              void* d_out, int out_size, void* d_ws, size_t ws_size,
                              hipStream_t stream)
{
    const float* x  = (const float*)d_in[0];
    const float* Wg = (const float*)d_in[1];
    const float* bg = (const float*)d_in[2];
    float* out = (float*)d_out;
    float* ws  = (float*)d_ws;    // ws[0..63] = f counts, ws[64..127] = m sums

    hipMemsetAsync(d_ws, 0, 2 * NE * sizeof(float), stream);

    const int grid = TOKENS / TB;   // 1024 blocks
    router_kernel<<<grid, 256, 0, stream>>>(x, Wg, bg, out, ws, ws + NE);
    aux_kernel<<<1, 64, 0, stream>>>(ws, ws + NE, out);
}

// Round 4
// 609.147 us; speedup vs baseline: 11.1386x; 11.1386x over previous
//
#include <hip/hip_runtime.h>
#include <math.h>

#define TOKENS 16384
#define HIDDEN 4096
#define NE 64
#define KSPLIT 8
#define KRANGE (HIDDEN / KSPLIT)     // 512
#define TB 256                       // tokens per block
#define KC 16                        // k per LDS chunk
#define CHUNKS (KRANGE / KC)         // 32

#define IDX_OFF 0
#define SC_OFF   (TOKENS * 2)
#define MASK_OFF (TOKENS * 4)
#define AUX_OFF  (MASK_OFF + TOKENS * 2 * NE)

#define P_FLOATS ((size_t)KSPLIT * TOKENS * NE)   // 8.39M floats = 33.5 MB

// Kernel 1: thread = token. W addresses are wave-uniform -> scalar pipe
// (s_load + v_fmac with SGPR operand). acc[64] constant-indexed = registers.
// Only per-thread "arrays" besides acc are xk[16] (LDS-fed) and g[4] float4
// prefetch regs. launch_bounds(256,2): 256-VGPR cap, spill impossible at ~110.
__global__ __launch_bounds__(256, 2)
void gemm_kernel(const float* __restrict__ x, const float* __restrict__ Wg,
                 float* __restrict__ P)
{
    const int tid = threadIdx.x;
    const int s   = blockIdx.x & 7;          // k-split: block i -> XCD i%8, W stripe stays in that L2
    const int tb  = blockIdx.x >> 3;         // token block 0..63
    const int t0  = tb * TB;
    const int k0  = s * KRANGE;

    __shared__ float xs[TB][KC + 1];         // stride 17: odd -> conflict-free

    // staging map: thread i -> rows {i/4 + 64q}, cols (i%4)*4 .. +3
    const int r0 = tid >> 2;
    const int c0 = (tid & 3) << 2;
    const float* xbase = x + (size_t)t0 * HIDDEN + k0 + c0;

    float acc[NE];
    #pragma unroll
    for (int e = 0; e < NE; ++e) acc[e] = 0.f;

    float4 g[4];
    #pragma unroll
    for (int q = 0; q < 4; ++q)
        g[q] = *reinterpret_cast<const float4*>(xbase + (size_t)(r0 + 64 * q) * HIDDEN);

    for (int c = 0; c < CHUNKS; ++c) {
        // commit staged regs to LDS (scalar stores: stride-17 rows aren't 16B-aligned)
        #pragma unroll
        for (int q = 0; q < 4; ++q) {
            xs[r0 + 64 * q][c0 + 0] = g[q].x;
            xs[r0 + 64 * q][c0 + 1] = g[q].y;
            xs[r0 + 64 * q][c0 + 2] = g[q].z;
            xs[r0 + 64 * q][c0 + 3] = g[q].w;
        }
        __syncthreads();

        if (c + 1 < CHUNKS) {                // prefetch next chunk during compute
            #pragma unroll
            for (int q = 0; q < 4; ++q)
                g[q] = *reinterpret_cast<const float4*>(
                    xbase + (size_t)(r0 + 64 * q) * HIDDEN + (c + 1) * KC);
        }

        float xk[KC];
        #pragma unroll
        for (int j = 0; j < KC; ++j) xk[j] = xs[tid][j];

        const float* wrow = Wg + (size_t)(k0 + c * KC) * NE;   // uniform
        #pragma unroll
        for (int e0 = 0; e0 < NE; e0 += 4) {
            #pragma unroll
            for (int j = 0; j < KC; ++j) {
                const float* wr = wrow + j * NE + e0;          // uniform -> s_load
                acc[e0 + 0] = fmaf(xk[j], wr[0], acc[e0 + 0]);
                acc[e0 + 1] = fmaf(xk[j], wr[1], acc[e0 + 1]);
                acc[e0 + 2] = fmaf(xk[j], wr[2], acc[e0 + 2]);
                acc[e0 + 3] = fmaf(xk[j], wr[3], acc[e0 + 3]);
            }
        }
        __syncthreads();
    }

    // deterministic fp32 partials: P[s][token][e]
    float* pout = P + ((size_t)s * TOKENS + t0 + tid) * NE;
    #pragma unroll
    for (int e = 0; e < NE; e += 4) {
        float4 v = make_float4(acc[e], acc[e + 1], acc[e + 2], acc[e + 3]);
        *reinterpret_cast<float4*>(pout + e) = v;
    }
}

// Kernel 2: sum 8 partials + R1's verified epilogue (lane = expert).
__global__ __launch_bounds__(256, 4)
void finish_kernel(const float* __restrict__ P, const float* __restrict__ bg,
                   float* __restrict__ out, float* __restrict__ gf,
                   float* __restrict__ gm)
{
    const int lane = threadIdx.x & 63;
    const int wv   = threadIdx.x >> 6;
    const int tbase = blockIdx.x * 32 + wv * 8;

    __shared__ float fsh[NE], msh[NE];
    if (threadIdx.x < NE) { fsh[threadIdx.x] = 0.f; msh[threadIdx.x] = 0.f; }
    __syncthreads();

    const float bias = bg[lane];
    float f_acc = 0.f, m_acc = 0.f;

    for (int t = 0; t < 8; ++t) {
        const int tok = tbase + t;
        float v = bias;
        #pragma unroll
        for (int sp = 0; sp < KSPLIT; ++sp)
            v += P[((size_t)sp * TOKENS + tok) * NE + lane];

        // top-1 (value desc, index asc — matches lax.top_k tie-break)
        float v1 = v; int i1 = lane;
        #pragma unroll
        for (int off = 32; off > 0; off >>= 1) {
            const float ov = __shfl_xor(v1, off, 64);
            const int   oi = __shfl_xor(i1, off, 64);
            if (ov > v1 || (ov == v1 && oi < i1)) { v1 = ov; i1 = oi; }
        }
        // top-2
        float v2 = (lane == i1) ? -INFINITY : v; int i2 = lane;
        #pragma unroll
        for (int off = 32; off > 0; off >>= 1) {
            const float ov = __shfl_xor(v2, off, 64);
            const int   oi = __shfl_xor(i2, off, 64);
            if (ov > v2 || (ov == v2 && oi < i2)) { v2 = ov; i2 = oi; }
        }

        // full 64-way softmax (for m_i)
        const float e = expf(v - v1);
        float sm = e;
        #pragma unroll
        for (int off = 32; off > 0; off >>= 1) sm += __shfl_xor(sm, off, 64);
        m_acc += e / sm;
        f_acc += ((lane == i1) ? 1.f : 0.f) + ((lane == i2) ? 1.f : 0.f);

        // softmax over top-2 (max v1 already subtracted)
        const float p  = expf(v2 - v1);
        const float s0 = 1.f / (1.f + p);
        const float s1 = p / (1.f + p);

        if (lane == 0) {
            out[IDX_OFF + tok * 2 + 0] = (float)i1;
            out[IDX_OFF + tok * 2 + 1] = (float)i2;
        } else if (lane == 1) {
            out[SC_OFF + tok * 2 + 0] = s0;
            out[SC_OFF + tok * 2 + 1] = s1;
        }
        out[MASK_OFF + (size_t)tok * 2 * NE + lane]      = (lane == i1) ? 1.f : 0.f;
        out[MASK_OFF + (size_t)tok * 2 * NE + NE + lane] = (lane == i2) ? 1.f : 0.f;
    }

    atomicAdd(&fsh[lane], f_acc);
    atomicAdd(&msh[lane], m_acc);
    __syncthreads();
    if (threadIdx.x < NE) {
        atomicAdd(&gf[threadIdx.x], fsh[threadIdx.x]);
        atomicAdd(&gm[threadIdx.x], msh[threadIdx.x]);
    }
}

// aux_loss = 0.01 * sum(f_i * m_i) / 64
__global__ void aux_kernel(const float* __restrict__ gf,
                           const float* __restrict__ gm,
                           float* __restrict__ out)
{
    const int lane = threadIdx.x;
    const float f = gf[lane] / (float)(TOKENS * 2);
    const float m = gm[lane] / (float)TOKENS;
    float p = f * m;
    #pragma unroll
    for (int off = 32; off > 0; off >>= 1) p += __shfl_xor(p, off, 64);
    if (lane == 0) out[AUX_OFF] = 0.01f * p / (float)NE;
}

extern "C" void kernel_launch(void* const* d_in, const int* in_sizes, int n_in,
                              void* d_out, int out_size, void* d_ws, size_t ws_size,
                              hipStream_t stream)
{
    const float* x  = (const float*)d_in[0];
    const float* Wg = (const float*)d_in[1];
    const float* bg = (const float*)d_in[2];
    float* out = (float*)d_out;
    float* P   = (float*)d_ws;                  // 33.5 MB partials
    float* gf  = P + P_FLOATS;                  // 64 f-counts
    float* gm  = gf + NE;                       // 64 m-sums

    hipMemsetAsync((char*)d_ws + P_FLOATS * sizeof(float), 0,
                   2 * NE * sizeof(float), stream);

    gemm_kernel<<<(TOKENS / TB) * KSPLIT, TB, 0, stream>>>(x, Wg, P);
    finish_kernel<<<TOKENS / 32, 256, 0, stream>>>(P, bg, out, gf, gm);
    aux_kernel<<<1, 64, 0, stream>>>(gf, gm, out);
}

// Round 5
// 460.719 us; speedup vs baseline: 14.7270x; 1.3222x over previous
//
#include <hip/hip_runtime.h>
#include <math.h>

#define TOKENS 16384
#define HIDDEN 4096
#define NE 64
#define KSPLIT 4
#define KRANGE (HIDDEN / KSPLIT)     // 1024
#define KSTEPS (KRANGE / 32)         // 32 K32-steps per wave

#define IDX_OFF 0
#define SC_OFF   (TOKENS * 2)
#define MASK_OFF (TOKENS * 4)
#define AUX_OFF  (MASK_OFF + TOKENS * 2 * NE)   // 2162688

#define KB_TOTAL (HIDDEN / 32)                  // 128 K32-blocks
#define WF_UINT4 (KB_TOTAL * 12 * 64)           // 98304 uint4 = 1.5 MB
#define P_FLOATS ((size_t)KSPLIT * TOKENS * NE) // 4.19M floats = 16.8 MB

typedef __attribute__((ext_vector_type(8))) short bf16x8;
typedef __attribute__((ext_vector_type(4))) float f32x4;
union U16x8 { uint4 u; bf16x8 v; };

// Exact truncation split: v == hi + mid + lo bit-exactly (hi/mid/lo are the
// top 3 bf16 "digits"); residual after lo < 2^-21 |v| is NOT dropped from v,
// only products mid*lo / lo*mid / lo*lo (<2^-24 rel) are dropped in the GEMM.
__device__ inline void split3(float v, unsigned short& h, unsigned short& m,
                              unsigned short& l)
{
    const unsigned bu = __float_as_uint(v);
    const float fh = __uint_as_float(bu & 0xffff0000u);
    const float r  = v - fh;                       // exact
    const unsigned br = __float_as_uint(r);
    const float fm = __uint_as_float(br & 0xffff0000u);
    const float r2 = r - fm;                       // exact
    h = (unsigned short)(bu >> 16);
    m = (unsigned short)(br >> 16);
    l = (unsigned short)(__float_as_uint(r2) >> 16);
}

// Pre-split W into MFMA B-fragment order:
// frag(kb, s, nt): 64 lanes x 16 B; lane holds B[k=kb*32+(lane>>4)*8+j][n=nt*16+(lane&15)]
__global__ void prep_w(const float* __restrict__ Wg, uint4* __restrict__ Wf)
{
    const int kb = blockIdx.x;             // 0..127
    const int nt = threadIdx.x >> 6;       // 0..3
    const int ln = threadIdx.x & 63;
    const int q  = ln >> 4;
    const int n  = nt * 16 + (ln & 15);

    U16x8 H, M, L;
    #pragma unroll
    for (int j = 0; j < 8; ++j) {
        const int k = kb * 32 + q * 8 + j;
        unsigned short h, m, l;
        split3(Wg[(size_t)k * NE + n], h, m, l);
        H.v[j] = (short)h; M.v[j] = (short)m; L.v[j] = (short)l;
    }
    uint4* base = Wf + (size_t)kb * 12 * 64 + ln;
    base[(0 * 4 + nt) * 64] = H.u;
    base[(1 * 4 + nt) * 64] = M.u;
    base[(2 * 4 + nt) * 64] = L.u;
}

// GEMM: wave = 16 tokens x 64 experts, K-split x4. A direct from global in
// fragment layout (x read exactly once), B frags from L2-resident Wf.
__global__ __launch_bounds__(256, 4)
void gemm_kernel(const float* __restrict__ x, const uint4* __restrict__ Wf,
                 float* __restrict__ P)
{
    const int lane = threadIdx.x & 63;
    const int wv   = threadIdx.x >> 6;
    const int ks   = blockIdx.x & (KSPLIT - 1);
    const int tb   = blockIdx.x >> 2;          // 0..255
    const int t0   = tb * 64 + wv * 16;
    const int k0   = ks * KRANGE;

    const int q    = lane >> 4;
    const int mrow = lane & 15;

    // A: lane reads x[t0+mrow][k0 + q*8 ..+7] -> rows' 128B fully coalesced
    const float* ap = x + (size_t)(t0 + mrow) * HIDDEN + k0 + q * 8;
    const uint4* wbase = Wf + (size_t)(k0 >> 5) * 12 * 64 + lane;

    f32x4 acc[4];
    #pragma unroll
    for (int nt = 0; nt < 4; ++nt) acc[nt] = (f32x4){0.f, 0.f, 0.f, 0.f};

    for (int kb = 0; kb < KSTEPS; ++kb) {
        // ---- B: 12 independent frag loads (3 splits x 4 n-tiles) ----
        U16x8 B[3][4];
        const uint4* wb = wbase + (size_t)kb * 12 * 64;
        #pragma unroll
        for (int s = 0; s < 3; ++s)
            #pragma unroll
            for (int nt = 0; nt < 4; ++nt)
                B[s][nt].u = wb[(s * 4 + nt) * 64];

        // ---- A: 8 fp32 -> 3 bf16 frags (exact truncation split) ----
        const float4 a01 = *reinterpret_cast<const float4*>(ap + (size_t)kb * 32);
        const float4 a23 = *reinterpret_cast<const float4*>(ap + (size_t)kb * 32 + 4);
        const float av[8] = {a01.x, a01.y, a01.z, a01.w, a23.x, a23.y, a23.z, a23.w};
        bf16x8 Ah, Am, Al;
        #pragma unroll
        for (int j = 0; j < 8; ++j) {
            unsigned short h, m, l;
            split3(av[j], h, m, l);
            Ah[j] = (short)h; Am[j] = (short)m; Al[j] = (short)l;
        }

        // ---- 24 MFMAs: 6 split-products x 4 n-tiles ----
        #pragma unroll
        for (int nt = 0; nt < 4; ++nt) {
            acc[nt] = __builtin_amdgcn_mfma_f32_16x16x32_bf16(Ah, B[0][nt].v, acc[nt], 0, 0, 0);
            acc[nt] = __builtin_amdgcn_mfma_f32_16x16x32_bf16(Ah, B[1][nt].v, acc[nt], 0, 0, 0);
            acc[nt] = __builtin_amdgcn_mfma_f32_16x16x32_bf16(Am, B[0][nt].v, acc[nt], 0, 0, 0);
            acc[nt] = __builtin_amdgcn_mfma_f32_16x16x32_bf16(Ah, B[2][nt].v, acc[nt], 0, 0, 0);
            acc[nt] = __builtin_amdgcn_mfma_f32_16x16x32_bf16(Am, B[1][nt].v, acc[nt], 0, 0, 0);
            acc[nt] = __builtin_amdgcn_mfma_f32_16x16x32_bf16(Al, B[0][nt].v, acc[nt], 0, 0, 0);
        }
    }

    // C/D layout (m89-verified): token = t0 + q*4 + r, expert = nt*16 + mrow
    float* prow = P + (size_t)ks * TOKENS * NE;
    #pragma unroll
    for (int nt = 0; nt < 4; ++nt)
        #pragma unroll
        for (int r = 0; r < 4; ++r)
            prow[(size_t)(t0 + q * 4 + r) * NE + nt * 16 + mrow] = acc[nt][r];
}

// Finish: sum 4 partials + verified lane=expert epilogue (R4, KSPLIT=4).
__global__ __launch_bounds__(256, 4)
void finish_kernel(const float* __restrict__ P, const float* __restrict__ bg,
                   float* __restrict__ out, float* __restrict__ gf,
                   float* __restrict__ gm)
{
    const int lane = threadIdx.x & 63;
    const int wv   = threadIdx.x >> 6;
    const int tbase = blockIdx.x * 32 + wv * 8;

    __shared__ float fsh[NE], msh[NE];
    if (threadIdx.x < NE) { fsh[threadIdx.x] = 0.f; msh[threadIdx.x] = 0.f; }
    __syncthreads();

    const float bias = bg[lane];
    float f_acc = 0.f, m_acc = 0.f;

    for (int t = 0; t < 8; ++t) {
        const int tok = tbase + t;
        float v = bias;
        #pragma unroll
        for (int sp = 0; sp < KSPLIT; ++sp)
            v += P[((size_t)sp * TOKENS + tok) * NE + lane];

        // top-1 (value desc, index asc — matches lax.top_k tie-break)
        float v1 = v; int i1 = lane;
        #pragma unroll
        for (int off = 32; off > 0; off >>= 1) {
            const float ov = __shfl_xor(v1, off, 64);
            const int   oi = __shfl_xor(i1, off, 64);
            if (ov > v1 || (ov == v1 && oi < i1)) { v1 = ov; i1 = oi; }
        }
        // top-2
        float v2 = (lane == i1) ? -INFINITY : v; int i2 = lane;
        #pragma unroll
        for (int off = 32; off > 0; off >>= 1) {
            const float ov = __shfl_xor(v2, off, 64);
            const int   oi = __shfl_xor(i2, off, 64);
            if (ov > v2 || (ov == v2 && oi < i2)) { v2 = ov; i2 = oi; }
        }

        // full 64-way softmax (for m_i)
        const float e = expf(v - v1);
        float sm = e;
        #pragma unroll
        for (int off = 32; off > 0; off >>= 1) sm += __shfl_xor(sm, off, 64);
        m_acc += e / sm;
        f_acc += ((lane == i1) ? 1.f : 0.f) + ((lane == i2) ? 1.f : 0.f);

        // softmax over top-2 (max v1 already subtracted)
        const float p  = expf(v2 - v1);
        const float s0 = 1.f / (1.f + p);
        const float s1 = p / (1.f + p);

        if (lane == 0) {
            out[IDX_OFF + tok * 2 + 0] = (float)i1;
            out[IDX_OFF + tok * 2 + 1] = (float)i2;
        } else if (lane == 1) {
            out[SC_OFF + tok * 2 + 0] = s0;
            out[SC_OFF + tok * 2 + 1] = s1;
        }
        out[MASK_OFF + (size_t)tok * 2 * NE + lane]      = (lane == i1) ? 1.f : 0.f;
        out[MASK_OFF + (size_t)tok * 2 * NE + NE + lane] = (lane == i2) ? 1.f : 0.f;
    }

    atomicAdd(&fsh[lane], f_acc);
    atomicAdd(&msh[lane], m_acc);
    __syncthreads();
    if (threadIdx.x < NE) {
        atomicAdd(&gf[threadIdx.x], fsh[threadIdx.x]);
        atomicAdd(&gm[threadIdx.x], msh[threadIdx.x]);
    }
}

// aux_loss = 0.01 * sum(f_i * m_i) / 64
__global__ void aux_kernel(const float* __restrict__ gf,
                           const float* __restrict__ gm,
                           float* __restrict__ out)
{
    const int lane = threadIdx.x;
    const float f = gf[lane] / (float)(TOKENS * 2);
    const float m = gm[lane] / (float)TOKENS;
    float p = f * m;
    #pragma unroll
    for (int off = 32; off > 0; off >>= 1) p += __shfl_xor(p, off, 64);
    if (lane == 0) out[AUX_OFF] = 0.01f * p / (float)NE;
}

extern "C" void kernel_launch(void* const* d_in, const int* in_sizes, int n_in,
                              void* d_out, int out_size, void* d_ws, size_t ws_size,
                              hipStream_t stream)
{
    const float* x  = (const float*)d_in[0];
    const float* Wg = (const float*)d_in[1];
    const float* bg = (const float*)d_in[2];
    float* out = (float*)d_out;

    uint4* Wf = (uint4*)d_ws;                         // 1.5 MB split-W frags
    float* P  = (float*)d_ws + (size_t)WF_UINT4 * 4;  // 16.8 MB partials
    float* gf = P + P_FLOATS;
    float* gm = gf + NE;

    hipMemsetAsync(gf, 0, 2 * NE * sizeof(float), stream);

    prep_w<<<KB_TOTAL, 256, 0, stream>>>(Wg, Wf);
    gemm_kernel<<<(TOKENS / 64) * KSPLIT, 256, 0, stream>>>(x, Wf, P);
    finish_kernel<<<TOKENS / 32, 256, 0, stream>>>(P, bg, out, gf, gm);
    aux_kernel<<<1, 64, 0, stream>>>(gf, gm, out);
}